// Round 2
// baseline (172.859 us; speedup 1.0000x reference)
//
#include <hip/hip_runtime.h>
#include <hip/hip_bf16.h>

// Problem (fp32 in/out): x[1][16][10][32][64][64], W[4][16][3][3][3][3], b[4]
// out[1][4][10][32][64][64] = softmax_over_channel(conv4d(x,W,pad=1)+b)
//
// R9 (re-bench; prior two rounds hit container infra failures): R8 +
// register-cached A-rows in COMPUTE. Per xt-column, rows wid4+0..5 are
// loaded ONCE (6 ds_read_b128 instead of 8); fa selected via cndmask on
// dyA, fb indexed statically. Cuts conv ds_read traffic 25%.
#define CIN  16
#define COUT 4
#define TT   10
#define ZZ   32
#define YY   64
#define XX   64

constexpr int SX_CI = TT * ZZ * YY * XX;  // 1310720
constexpr int SX_T  = ZZ * YY * XX;       // 131072
constexpr int SX_Z  = YY * XX;            // 4096
constexpr int WCO   = CIN * 81;           // 1296

constexpr int XT_TB = ZZ * YY * XX * CIN * 2;  // 4194304
constexpr int XT_ZB = YY * XX * CIN * 2;       // 131072
constexpr int XT_YB = XX * CIN * 2;            // 2048 (one row)
constexpr size_t XT_BYTES = (size_t)TT * XT_TB;    // 41,943,040
constexpr size_t BTAB     = XT_BYTES;              // 9 planes x 2 frags x 1KB
constexpr size_t ZOFF     = BTAB + 9 * 2048;       // 2048B zero row
constexpr size_t WS_NEED  = ZOFF + 2048;

typedef short  short8 __attribute__((ext_vector_type(8)));
typedef float  f32x4  __attribute__((ext_vector_type(4)));

__device__ __forceinline__ unsigned short f2bf(float f) {
    union { __hip_bfloat16 h; unsigned short u; } c;
    c.h = __float2bfloat16(f);
    return c.u;
}
__device__ __forceinline__ unsigned int pk(float a, float b) {
    return (unsigned int)f2bf(a) | ((unsigned int)f2bf(b) << 16);
}

// ---- transpose v4 (R7, ~fine): LDS-tiled, both global sides coalesced ----
#define TXS 36
#define TYS (64 * TXS)
__global__ __launch_bounds__(256) void transpose_x(const float* __restrict__ x,
                                                   char* __restrict__ ws) {
    __shared__ char lds[16 * TYS];   // 36,864 B
    const int lane = threadIdx.x & 63;
    const int w    = threadIdx.x >> 6;
    const int yq = blockIdx.x, z = blockIdx.y, t = blockIdx.z;
    const int y0 = yq * 16;
    const int rl = w * 4 + (lane >> 4);
    const int x0 = (lane & 15) * 4;
    const size_t gbase = (size_t)t * SX_T + (size_t)z * SX_Z +
                         (size_t)(y0 + rl) * XX + x0;
#pragma unroll
    for (int cp = 0; cp < 8; ++cp) {
        const float4 f0 = *(const float4*)(x + (size_t)(2 * cp + 0) * SX_CI + gbase);
        const float4 f1 = *(const float4*)(x + (size_t)(2 * cp + 1) * SX_CI + gbase);
        char* p = lds + rl * TYS + x0 * TXS + cp * 4;
        *(unsigned int*)(p + 0 * TXS) = pk(f0.x, f1.x);
        *(unsigned int*)(p + 1 * TXS) = pk(f0.y, f1.y);
        *(unsigned int*)(p + 2 * TXS) = pk(f0.z, f1.z);
        *(unsigned int*)(p + 3 * TXS) = pk(f0.w, f1.w);
    }
    __syncthreads();
#pragma unroll
    for (int s = 0; s < 4; ++s) {
        const int r2 = w * 4 + s;
        char* rowp = ws + (((size_t)t * ZZ + z) * YY + (y0 + r2)) * 2048;
#pragma unroll
        for (int half = 0; half < 2; ++half) {
            const int c = half * 64 + lane;
            const uint4 d = *(const uint4*)(lds + r2 * TYS + (c >> 1) * TXS +
                                            (c & 1) * 16);
            *(uint4*)(rowp + c * 16) = d;
        }
    }
}

// ---- prep: B-fragment tables + zero row (verified R7) ----
__global__ void prep_B(const float* __restrict__ W, char* __restrict__ ws) {
    const int g = blockIdx.x * 256 + threadIdx.x;
    if (g < 1152) {
        const int p = g >> 7, rem = g & 127, frag = rem >> 6, L = rem & 63;
        const int q = L >> 4, n = L & 15, co = n & 3, dx = n >> 2;
        const int dt = p / 3, dz = p % 3;
        unsigned int d[4];
#pragma unroll
        for (int j = 0; j < 4; ++j) {
            float v0 = 0.f, v1 = 0.f;
            if (dx < 3) {
                if (frag == 0) {
                    const int dy = q >> 1;
                    const int ci0 = (q & 1) * 8 + 2 * j;
                    v0 = W[(co * CIN + ci0) * 81 + dt * 27 + dz * 9 + dy * 3 + dx];
                    v1 = W[(co * CIN + ci0 + 1) * 81 + dt * 27 + dz * 9 + dy * 3 + dx];
                } else if (q < 2) {
                    const int ci0 = q * 8 + 2 * j;
                    v0 = W[(co * CIN + ci0) * 81 + dt * 27 + dz * 9 + 6 + dx];
                    v1 = W[(co * CIN + ci0 + 1) * 81 + dt * 27 + dz * 9 + 6 + dx];
                }
            }
            d[j] = pk(v0, v1);
        }
        *(uint4*)(ws + BTAB + (size_t)p * 2048 + frag * 1024 + (size_t)L * 16) =
            make_uint4(d[0], d[1], d[2], d[3]);
    } else if (g < 1280) {
        *(uint4*)(ws + ZOFF + (size_t)(g - 1152) * 16) = make_uint4(0, 0, 0, 0);
    }
}

#define GL16(SRC, DST) __builtin_amdgcn_global_load_lds( \
    (const __attribute__((address_space(1))) unsigned int*)(SRC), \
    (__attribute__((address_space(3))) unsigned int*)(DST), 16, 0, 0)

#define LROW 21
__global__ __launch_bounds__(256, 2) void conv_mfma(
        const char* __restrict__ ws,
        const float* __restrict__ bias,
        float* __restrict__ out) {
    __shared__ char smem[2 * 18 * 2048];   // 73,728 B double buffer (2 blk/CU)
    const int lane = threadIdx.x;
    const int wid  = __builtin_amdgcn_readfirstlane(threadIdx.y);
    // XCD swizzle: z-slab per XCD, t-major order -> halo working set ~2.3MB < L2
    const int bid = blockIdx.x;
    const int xcd = bid & 7, lid = bid >> 3;
    const int z0 = 4 * xcd + (lid & 3);
    const int yq = (lid >> 2) & 3;
    const int t0 = lid >> 4;
    const int y0 = yq * 16;
    const int m = lane & 15, q = lane >> 4, h = q & 1, dyA = q >> 1;
    const int e2 = 2 * m + h;
    const int wid4 = wid * 4;

    f32x4 acc[4][4];
#pragma unroll
    for (int r = 0; r < 4; ++r)
#pragma unroll
        for (int xt = 0; xt < 4; ++xt) acc[r][xt] = (f32x4){0.f, 0.f, 0.f, 0.f};

// Stage plane P into buffer BUF. Wave w, iter k: half-row rw=(w+4k)>>1,
// half=(w+4k)&1 (wave-uniform base + lane*16). OOB rows/planes -> zero row.
#define STAGE(P, BUF) { \
    const int dtS = (P) / 3, dzS = (P) % 3; \
    const int t_in = t0 + dtS - 1, z_in = z0 + dzS - 1; \
    const bool pv = ((unsigned)t_in < TT) && ((unsigned)z_in < ZZ); \
    const int pbase = pv ? (t_in * XT_TB + z_in * XT_ZB) : 0; \
    _Pragma("unroll") \
    for (int k = 0; k < 9; ++k) { \
        const int rw = (wid + 4 * k) >> 1; \
        const int hf = ((wid + 4 * k) & 1) * 1024; \
        const int y_in = y0 - 1 + rw; \
        const bool rv = pv && ((unsigned)y_in < YY); \
        const char* srcS = ws + (rv ? (size_t)(pbase + y_in * XT_YB) : ZOFF) \
                              + hf + lane * 16; \
        GL16(srcS, smem + (BUF) * 36864 + rw * 2048 + hf + lane * 16); \
    } }

// Compute plane P from buffer BUF. fragB k>=16 is zero IN B (no masking).
// R9: per xt-column, the 4x(fa,fb) pairs touch only 6 unique rows
// (wid4+0..5, all staged). Load them once into Rw[], select fa by dyA
// (4 v_cndmask), index fb statically. 24 ds_read_b128/plane vs 32.
#define COMPUTE(P, BUF) { \
    const char* bbC = smem + (BUF) * 36864; \
    const short8 BfA = *(const short8*)(ws + BTAB + (P) * 2048 + lane * 16); \
    const short8 BfB = *(const short8*)(ws + BTAB + (P) * 2048 + 1024 + lane * 16); \
    _Pragma("unroll") \
    for (int xt = 0; xt < 4; ++xt) { \
        const int sw = (32 * xt + e2) * 16; \
        const char* colp = bbC + wid4 * 2048 + sw; \
        short8 Rw0 = *(const short8*)(colp + 0 * 2048); \
        short8 Rw1 = *(const short8*)(colp + 1 * 2048); \
        short8 Rw2 = *(const short8*)(colp + 2 * 2048); \
        short8 Rw3 = *(const short8*)(colp + 3 * 2048); \
        short8 Rw4 = *(const short8*)(colp + 4 * 2048); \
        short8 Rw5 = *(const short8*)(colp + 5 * 2048); \
        const short8 fa0 = dyA ? Rw1 : Rw0; \
        const short8 fa1 = dyA ? Rw2 : Rw1; \
        const short8 fa2 = dyA ? Rw3 : Rw2; \
        const short8 fa3 = dyA ? Rw4 : Rw3; \
        acc[0][xt] = __builtin_amdgcn_mfma_f32_16x16x32_bf16(fa0, BfA, acc[0][xt], 0, 0, 0); \
        acc[0][xt] = __builtin_amdgcn_mfma_f32_16x16x32_bf16(Rw2, BfB, acc[0][xt], 0, 0, 0); \
        acc[1][xt] = __builtin_amdgcn_mfma_f32_16x16x32_bf16(fa1, BfA, acc[1][xt], 0, 0, 0); \
        acc[1][xt] = __builtin_amdgcn_mfma_f32_16x16x32_bf16(Rw3, BfB, acc[1][xt], 0, 0, 0); \
        acc[2][xt] = __builtin_amdgcn_mfma_f32_16x16x32_bf16(fa2, BfA, acc[2][xt], 0, 0, 0); \
        acc[2][xt] = __builtin_amdgcn_mfma_f32_16x16x32_bf16(Rw4, BfB, acc[2][xt], 0, 0, 0); \
        acc[3][xt] = __builtin_amdgcn_mfma_f32_16x16x32_bf16(fa3, BfA, acc[3][xt], 0, 0, 0); \
        acc[3][xt] = __builtin_amdgcn_mfma_f32_16x16x32_bf16(Rw5, BfB, acc[3][xt], 0, 0, 0); \
    } }

    // Pipeline: barrier AFTER compute -> stage(P+1) flies under compute(P).
    STAGE(0, 0) __syncthreads();
    STAGE(1, 1) COMPUTE(0, 0) __syncthreads();
    STAGE(2, 0) COMPUTE(1, 1) __syncthreads();
    STAGE(3, 1) COMPUTE(2, 0) __syncthreads();
    STAGE(4, 0) COMPUTE(3, 1) __syncthreads();
    STAGE(5, 1) COMPUTE(4, 0) __syncthreads();
    STAGE(6, 0) COMPUTE(5, 1) __syncthreads();
    STAGE(7, 1) COMPUTE(6, 0) __syncthreads();
    STAGE(8, 0) COMPUTE(7, 1) __syncthreads();
    COMPUTE(8, 0) __syncthreads();
#undef STAGE
#undef COMPUTE

    const float bi0 = bias[0], bi1 = bias[1], bi2 = bias[2], bi3 = bias[3];
    float* swave = (float*)smem + wid * (66 * LROW);   // aliases dead staging
    if (lane < LROW) {
        swave[lane] = 0.f;
        swave[65 * LROW + lane] = 0.f;
    }
    const int colw = lane & 15;
    const int rowq = (lane >> 4) * 4 + 1;
#pragma unroll
    for (int r = 0; r < 4; ++r) {
#pragma unroll
        for (int xt = 0; xt < 4; ++xt)
#pragma unroll
            for (int reg = 0; reg < 4; ++reg)
                swave[(xt * 16 + rowq + reg) * LROW + colw] = acc[r][xt][reg];
        float lg0 = bi0, lg1 = bi1, lg2 = bi2, lg3 = bi3;
#pragma unroll
        for (int dx = 0; dx < 3; ++dx) {
            const float* sp = swave + (lane + dx) * LROW + dx * 4;
            lg0 += sp[0]; lg1 += sp[1]; lg2 += sp[2]; lg3 += sp[3];
        }
        const float mx = fmaxf(fmaxf(lg0, lg1), fmaxf(lg2, lg3));
        const float e0 = __expf(lg0 - mx);
        const float e1 = __expf(lg1 - mx);
        const float e2v = __expf(lg2 - mx);
        const float e3 = __expf(lg3 - mx);
        const float inv = 1.f / (e0 + e1 + e2v + e3);
        const int y = y0 + wid4 + r;
        float* op = out + (size_t)t0 * SX_T + (size_t)z0 * SX_Z + (size_t)y * XX + lane;
        op[0 * (size_t)SX_CI] = e0 * inv;
        op[1 * (size_t)SX_CI] = e1 * inv;
        op[2 * (size_t)SX_CI] = e2v * inv;
        op[3 * (size_t)SX_CI] = e3 * inv;
    }
}

// ================= fallback (R3 vector kernel) if ws too small =================
__global__ __launch_bounds__(256, 4) void conv4d_softmax_vec(
        const float* __restrict__ x, const float* __restrict__ W,
        const float* __restrict__ b, float* __restrict__ out) {
    const int lane = threadIdx.x;
    const int xg = lane & 15, yl = lane >> 4;
    const int y = blockIdx.x * 16 + threadIdx.y * 4 + yl;
    const int z0 = blockIdx.y, t0 = blockIdx.z, x0 = xg * 4;
    float acc[COUT][4];
#pragma unroll
    for (int c = 0; c < COUT; ++c)
#pragma unroll
        for (int xi = 0; xi < 4; ++xi) acc[c][xi] = 0.f;
    for (int ci = 0; ci < CIN; ++ci) {
        const float* xc = x + (size_t)ci * SX_CI;
        const float* wc = W + ci * 81;
#pragma unroll
        for (int dt = 0; dt < 3; ++dt) {
            const int t_in = t0 + dt - 1;
            const int t_c = min(max(t_in, 0), TT - 1);
            const bool tv = (unsigned)t_in < TT;
#pragma unroll
            for (int dz = 0; dz < 3; ++dz) {
                const int z_in = z0 + dz - 1;
                const int z_c = min(max(z_in, 0), ZZ - 1);
                const bool tzvv = tv && ((unsigned)z_in < ZZ);
                const float* plane = xc + (size_t)t_c * SX_T + (size_t)z_c * SX_Z;
                const float* wb = wc + (dt * 3 + dz) * 9;
#pragma unroll
                for (int e = 0; e < 3; ++e) {
                    const int y_in = y + e - 1;
                    const int y_c = min(max(y_in, 0), YY - 1);
                    const bool v = tzvv && ((unsigned)y_in < YY);
                    float4 f = *(const float4*)(plane + y_c * XX + x0);
                    f.x = v ? f.x : 0.f; f.y = v ? f.y : 0.f;
                    f.z = v ? f.z : 0.f; f.w = v ? f.w : 0.f;
                    float hl = __shfl(f.w, (lane - 1) & 63, 64);
                    hl = (xg == 0) ? 0.f : hl;
                    float hr = __shfl(f.x, (lane + 1) & 63, 64);
                    hr = (xg == 15) ? 0.f : hr;
                    const float win[6] = {hl, f.x, f.y, f.z, f.w, hr};
#pragma unroll
                    for (int co = 0; co < COUT; ++co) {
                        const float* wp = wb + co * WCO + e * 3;
                        const float w0 = wp[0], w1 = wp[1], w2 = wp[2];
#pragma unroll
                        for (int xi = 0; xi < 4; ++xi) {
                            float a = acc[co][xi];
                            a = fmaf(win[xi], w0, a);
                            a = fmaf(win[xi + 1], w1, a);
                            a = fmaf(win[xi + 2], w2, a);
                            acc[co][xi] = a;
                        }
                    }
                }
            }
        }
    }
    const float b0 = b[0], b1 = b[1], b2 = b[2], b3 = b[3];
    float4 rr[COUT];
#pragma unroll
    for (int xi = 0; xi < 4; ++xi) {
        const float a0 = acc[0][xi] + b0, a1 = acc[1][xi] + b1;
        const float a2 = acc[2][xi] + b2, a3 = acc[3][xi] + b3;
        const float mm = fmaxf(fmaxf(a0, a1), fmaxf(a2, a3));
        const float e0 = __expf(a0 - mm), e1 = __expf(a1 - mm);
        const float e2 = __expf(a2 - mm), e3 = __expf(a3 - mm);
        const float inv = 1.f / (e0 + e1 + e2 + e3);
        ((float*)&rr[0])[xi] = e0 * inv; ((float*)&rr[1])[xi] = e1 * inv;
        ((float*)&rr[2])[xi] = e2 * inv; ((float*)&rr[3])[xi] = e3 * inv;
    }
    float* op = out + (size_t)t0 * SX_T + (size_t)z0 * SX_Z + (size_t)y * XX + x0;
#pragma unroll
    for (int co = 0; co < COUT; ++co)
        *(float4*)(op + (size_t)co * SX_CI) = rr[co];
}

extern "C" void kernel_launch(void* const* d_in, const int* in_sizes, int n_in,
                              void* d_out, int out_size, void* d_ws, size_t ws_size,
                              hipStream_t stream) {
    const float* x = (const float*)d_in[0];
    const float* W = (const float*)d_in[1];
    const float* b = (const float*)d_in[2];
    float* out = (float*)d_out;

    if (ws_size >= WS_NEED) {
        char* ws = (char*)d_ws;
        transpose_x<<<dim3(4, ZZ, TT), dim3(256), 0, stream>>>(x, ws);
        prep_B<<<dim3(5), dim3(256), 0, stream>>>(W, ws);
        conv_mfma<<<dim3(1280), dim3(64, 4), 0, stream>>>(ws, b, out);
    } else {
        conv4d_softmax_vec<<<dim3(4, ZZ, TT), dim3(64, 4), 0, stream>>>(x, W, b, out);
    }
}

// Round 3
// 164.478 us; speedup vs baseline: 1.0510x; 1.0510x over previous
//
#include <hip/hip_runtime.h>
#include <hip/hip_bf16.h>

// Problem (fp32 in/out): x[1][16][10][32][64][64], W[4][16][3][3][3][3], b[4]
// out[1][4][10][32][64][64] = softmax_over_channel(conv4d(x,W,pad=1)+b)
//
// R10: z-PAIR blocks. Each block computes (z0,z0+1) x 8 y-rows x 64 x x 4 co.
// 12-plane loop (3 dt x 4 z-inputs); interior planes feed both z-accs from the
// SAME A-rows (Rw0..3 shared, only B-frags differ by dz shift). Plane buffer
// 10 rows x 2KB, double-buffered = 40,960 B -> 4 blocks/CU (160 KiB exactly).
// vs R9: staging -26%, ds_read -11%, MFMA same, occupancy 2x.
#define CIN  16
#define COUT 4
#define TT   10
#define ZZ   32
#define YY   64
#define XX   64

constexpr int SX_CI = TT * ZZ * YY * XX;  // 1310720
constexpr int SX_T  = ZZ * YY * XX;       // 131072
constexpr int SX_Z  = YY * XX;            // 4096
constexpr int WCO   = CIN * 81;           // 1296

constexpr int XT_TB = ZZ * YY * XX * CIN * 2;  // 4194304
constexpr int XT_ZB = YY * XX * CIN * 2;       // 131072
constexpr int XT_YB = XX * CIN * 2;            // 2048 (one row)
constexpr size_t XT_BYTES = (size_t)TT * XT_TB;    // 41,943,040
constexpr size_t BTAB     = XT_BYTES;              // 9 planes x 2 frags x 1KB
constexpr size_t ZOFF     = BTAB + 9 * 2048;       // 2048B zero row
constexpr size_t WS_NEED  = ZOFF + 2048;

typedef short  short8 __attribute__((ext_vector_type(8)));
typedef float  f32x4  __attribute__((ext_vector_type(4)));

__device__ __forceinline__ unsigned short f2bf(float f) {
    union { __hip_bfloat16 h; unsigned short u; } c;
    c.h = __float2bfloat16(f);
    return c.u;
}
__device__ __forceinline__ unsigned int pk(float a, float b) {
    return (unsigned int)f2bf(a) | ((unsigned int)f2bf(b) << 16);
}

// ---- transpose v4 (R7, ~fine): LDS-tiled, both global sides coalesced ----
#define TXS 36
#define TYS (64 * TXS)
__global__ __launch_bounds__(256) void transpose_x(const float* __restrict__ x,
                                                   char* __restrict__ ws) {
    __shared__ char lds[16 * TYS];   // 36,864 B
    const int lane = threadIdx.x & 63;
    const int w    = threadIdx.x >> 6;
    const int yq = blockIdx.x, z = blockIdx.y, t = blockIdx.z;
    const int y0 = yq * 16;
    const int rl = w * 4 + (lane >> 4);
    const int x0 = (lane & 15) * 4;
    const size_t gbase = (size_t)t * SX_T + (size_t)z * SX_Z +
                         (size_t)(y0 + rl) * XX + x0;
#pragma unroll
    for (int cp = 0; cp < 8; ++cp) {
        const float4 f0 = *(const float4*)(x + (size_t)(2 * cp + 0) * SX_CI + gbase);
        const float4 f1 = *(const float4*)(x + (size_t)(2 * cp + 1) * SX_CI + gbase);
        char* p = lds + rl * TYS + x0 * TXS + cp * 4;
        *(unsigned int*)(p + 0 * TXS) = pk(f0.x, f1.x);
        *(unsigned int*)(p + 1 * TXS) = pk(f0.y, f1.y);
        *(unsigned int*)(p + 2 * TXS) = pk(f0.z, f1.z);
        *(unsigned int*)(p + 3 * TXS) = pk(f0.w, f1.w);
    }
    __syncthreads();
#pragma unroll
    for (int s = 0; s < 4; ++s) {
        const int r2 = w * 4 + s;
        char* rowp = ws + (((size_t)t * ZZ + z) * YY + (y0 + r2)) * 2048;
#pragma unroll
        for (int half = 0; half < 2; ++half) {
            const int c = half * 64 + lane;
            const uint4 d = *(const uint4*)(lds + r2 * TYS + (c >> 1) * TXS +
                                            (c & 1) * 16);
            *(uint4*)(rowp + c * 16) = d;
        }
    }
}

// ---- prep: B-fragment tables + zero row (verified R7) ----
__global__ void prep_B(const float* __restrict__ W, char* __restrict__ ws) {
    const int g = blockIdx.x * 256 + threadIdx.x;
    if (g < 1152) {
        const int p = g >> 7, rem = g & 127, frag = rem >> 6, L = rem & 63;
        const int q = L >> 4, n = L & 15, co = n & 3, dx = n >> 2;
        const int dt = p / 3, dz = p % 3;
        unsigned int d[4];
#pragma unroll
        for (int j = 0; j < 4; ++j) {
            float v0 = 0.f, v1 = 0.f;
            if (dx < 3) {
                if (frag == 0) {
                    const int dy = q >> 1;
                    const int ci0 = (q & 1) * 8 + 2 * j;
                    v0 = W[(co * CIN + ci0) * 81 + dt * 27 + dz * 9 + dy * 3 + dx];
                    v1 = W[(co * CIN + ci0 + 1) * 81 + dt * 27 + dz * 9 + dy * 3 + dx];
                } else if (q < 2) {
                    const int ci0 = q * 8 + 2 * j;
                    v0 = W[(co * CIN + ci0) * 81 + dt * 27 + dz * 9 + 6 + dx];
                    v1 = W[(co * CIN + ci0 + 1) * 81 + dt * 27 + dz * 9 + 6 + dx];
                }
            }
            d[j] = pk(v0, v1);
        }
        *(uint4*)(ws + BTAB + (size_t)p * 2048 + frag * 1024 + (size_t)L * 16) =
            make_uint4(d[0], d[1], d[2], d[3]);
    } else if (g < 1280) {
        *(uint4*)(ws + ZOFF + (size_t)(g - 1152) * 16) = make_uint4(0, 0, 0, 0);
    }
}

#define GL16(SRC, DST) __builtin_amdgcn_global_load_lds( \
    (const __attribute__((address_space(1))) unsigned int*)(SRC), \
    (__attribute__((address_space(3))) unsigned int*)(DST), 16, 0, 0)

#define LROW 21
__global__ __launch_bounds__(256, 4) void conv_mfma(
        const char* __restrict__ ws,
        const float* __restrict__ bias,
        float* __restrict__ out) {
    __shared__ char smem[2 * 10 * 2048];   // 40,960 B double buffer -> 4 blk/CU
    const int lane = threadIdx.x;
    const int wid  = __builtin_amdgcn_readfirstlane(threadIdx.y);
    // XCD swizzle: z-slab (4 z) per XCD, t-major order
    const int bid = blockIdx.x;
    const int xcd = bid & 7, lid = bid >> 3;   // lid 0..159
    const int z0 = 4 * xcd + 2 * (lid & 1);    // even z; block does z0, z0+1
    const int yq = (lid >> 1) & 7;
    const int t0 = lid >> 4;
    const int y0 = yq * 8;
    const int m = lane & 15, q = lane >> 4, h = q & 1, dyA = q >> 1;
    const int e2 = 2 * m + h;
    const int wid2 = wid * 2;

    f32x4 acc[2][2][4];   // [z][r][xt]
#pragma unroll
    for (int z = 0; z < 2; ++z)
#pragma unroll
        for (int r = 0; r < 2; ++r)
#pragma unroll
            for (int xt = 0; xt < 4; ++xt) acc[z][r][xt] = (f32x4){0.f, 0.f, 0.f, 0.f};

// Stage plane P (dt=P>>2, zin=z0-1+(P&3)) into buffer BUF: 10 rows x 2KB.
// 20 half-row loads over 4 waves (5/wave). OOB rows/planes -> zero row.
#define STAGE(P, BUF) { \
    constexpr int dtS = (P) >> 2, jS = (P) & 3; \
    const int t_in = t0 + dtS - 1, z_in = z0 + jS - 1; \
    const bool pv = ((unsigned)t_in < TT) && ((unsigned)z_in < ZZ); \
    const int pbase = pv ? (t_in * XT_TB + z_in * XT_ZB) : 0; \
    _Pragma("unroll") \
    for (int k = 0; k < 5; ++k) { \
        const int idx = wid + 4 * k; \
        const int rw = idx >> 1; \
        const int hf = (idx & 1) * 1024; \
        const int y_in = y0 - 1 + rw; \
        const bool rv = pv && ((unsigned)y_in < YY); \
        const char* srcS = ws + (rv ? (size_t)(pbase + y_in * XT_YB) : ZOFF) \
                              + hf + lane * 16; \
        GL16(srcS, smem + (BUF) * 20480 + rw * 2048 + hf + lane * 16); \
    } }

// Compute plane P from buffer BUF. Plane j contributes to z0 (dz=j, j<=2) and
// z1 (dz=j-1, j>=1) -- SAME A-rows (Rw0..3), different B-frags. Static gating
// (P literal) folds the branches.
#define COMPUTE(P, BUF) { \
    constexpr int dtC = (P) >> 2, jC = (P) & 3; \
    constexpr int paC = dtC * 3 + (jC <= 2 ? jC : 0); \
    constexpr int pbC = dtC * 3 + (jC >= 1 ? jC - 1 : 0); \
    const char* bbC = smem + (BUF) * 20480; \
    const short8 BfAa = *(const short8*)(ws + BTAB + paC * 2048 + lane * 16); \
    const short8 BfBa = *(const short8*)(ws + BTAB + paC * 2048 + 1024 + lane * 16); \
    const short8 BfAb = *(const short8*)(ws + BTAB + pbC * 2048 + lane * 16); \
    const short8 BfBb = *(const short8*)(ws + BTAB + pbC * 2048 + 1024 + lane * 16); \
    _Pragma("unroll") \
    for (int xt = 0; xt < 4; ++xt) { \
        const int sw = (32 * xt + e2) * 16; \
        const char* colp = bbC + wid2 * 2048 + sw; \
        const short8 Rw0 = *(const short8*)(colp + 0 * 2048); \
        const short8 Rw1 = *(const short8*)(colp + 1 * 2048); \
        const short8 Rw2 = *(const short8*)(colp + 2 * 2048); \
        const short8 Rw3 = *(const short8*)(colp + 3 * 2048); \
        const short8 fa0 = dyA ? Rw1 : Rw0; \
        const short8 fa1 = dyA ? Rw2 : Rw1; \
        if (jC <= 2) { \
            acc[0][0][xt] = __builtin_amdgcn_mfma_f32_16x16x32_bf16(fa0, BfAa, acc[0][0][xt], 0, 0, 0); \
            acc[0][0][xt] = __builtin_amdgcn_mfma_f32_16x16x32_bf16(Rw2, BfBa, acc[0][0][xt], 0, 0, 0); \
            acc[0][1][xt] = __builtin_amdgcn_mfma_f32_16x16x32_bf16(fa1, BfAa, acc[0][1][xt], 0, 0, 0); \
            acc[0][1][xt] = __builtin_amdgcn_mfma_f32_16x16x32_bf16(Rw3, BfBa, acc[0][1][xt], 0, 0, 0); \
        } \
        if (jC >= 1) { \
            acc[1][0][xt] = __builtin_amdgcn_mfma_f32_16x16x32_bf16(fa0, BfAb, acc[1][0][xt], 0, 0, 0); \
            acc[1][0][xt] = __builtin_amdgcn_mfma_f32_16x16x32_bf16(Rw2, BfBb, acc[1][0][xt], 0, 0, 0); \
            acc[1][1][xt] = __builtin_amdgcn_mfma_f32_16x16x32_bf16(fa1, BfAb, acc[1][1][xt], 0, 0, 0); \
            acc[1][1][xt] = __builtin_amdgcn_mfma_f32_16x16x32_bf16(Rw3, BfBb, acc[1][1][xt], 0, 0, 0); \
        } \
    } }

    // Pipeline: barrier AFTER compute -> stage(P+1) flies under compute(P).
    STAGE(0, 0)  __syncthreads();
    STAGE(1, 1)  COMPUTE(0, 0)  __syncthreads();
    STAGE(2, 0)  COMPUTE(1, 1)  __syncthreads();
    STAGE(3, 1)  COMPUTE(2, 0)  __syncthreads();
    STAGE(4, 0)  COMPUTE(3, 1)  __syncthreads();
    STAGE(5, 1)  COMPUTE(4, 0)  __syncthreads();
    STAGE(6, 0)  COMPUTE(5, 1)  __syncthreads();
    STAGE(7, 1)  COMPUTE(6, 0)  __syncthreads();
    STAGE(8, 0)  COMPUTE(7, 1)  __syncthreads();
    STAGE(9, 1)  COMPUTE(8, 0)  __syncthreads();
    STAGE(10, 0) COMPUTE(9, 1)  __syncthreads();
    STAGE(11, 1) COMPUTE(10, 0) __syncthreads();
    COMPUTE(11, 1) __syncthreads();
#undef STAGE
#undef COMPUTE

    const float bi0 = bias[0], bi1 = bias[1], bi2 = bias[2], bi3 = bias[3];
    float* swave = (float*)smem + wid * (66 * LROW);   // aliases dead staging
    if (lane < LROW) {
        swave[lane] = 0.f;
        swave[65 * LROW + lane] = 0.f;
    }
    const int colw = lane & 15;
    const int rowq = (lane >> 4) * 4 + 1;
#pragma unroll
    for (int z = 0; z < 2; ++z) {
#pragma unroll
        for (int r = 0; r < 2; ++r) {
#pragma unroll
            for (int xt = 0; xt < 4; ++xt)
#pragma unroll
                for (int reg = 0; reg < 4; ++reg)
                    swave[(xt * 16 + rowq + reg) * LROW + colw] = acc[z][r][xt][reg];
            float lg0 = bi0, lg1 = bi1, lg2 = bi2, lg3 = bi3;
#pragma unroll
            for (int dx = 0; dx < 3; ++dx) {
                const float* sp = swave + (lane + dx) * LROW + dx * 4;
                lg0 += sp[0]; lg1 += sp[1]; lg2 += sp[2]; lg3 += sp[3];
            }
            const float mx = fmaxf(fmaxf(lg0, lg1), fmaxf(lg2, lg3));
            const float e0 = __expf(lg0 - mx);
            const float e1 = __expf(lg1 - mx);
            const float e2v = __expf(lg2 - mx);
            const float e3 = __expf(lg3 - mx);
            const float inv = 1.f / (e0 + e1 + e2v + e3);
            const int y = y0 + wid2 + r;
            float* op = out + (size_t)t0 * SX_T + (size_t)(z0 + z) * SX_Z +
                        (size_t)y * XX + lane;
            op[0 * (size_t)SX_CI] = e0 * inv;
            op[1 * (size_t)SX_CI] = e1 * inv;
            op[2 * (size_t)SX_CI] = e2v * inv;
            op[3 * (size_t)SX_CI] = e3 * inv;
        }
    }
}

// ================= fallback (R3 vector kernel) if ws too small =================
__global__ __launch_bounds__(256, 4) void conv4d_softmax_vec(
        const float* __restrict__ x, const float* __restrict__ W,
        const float* __restrict__ b, float* __restrict__ out) {
    const int lane = threadIdx.x;
    const int xg = lane & 15, yl = lane >> 4;
    const int y = blockIdx.x * 16 + threadIdx.y * 4 + yl;
    const int z0 = blockIdx.y, t0 = blockIdx.z, x0 = xg * 4;
    float acc[COUT][4];
#pragma unroll
    for (int c = 0; c < COUT; ++c)
#pragma unroll
        for (int xi = 0; xi < 4; ++xi) acc[c][xi] = 0.f;
    for (int ci = 0; ci < CIN; ++ci) {
        const float* xc = x + (size_t)ci * SX_CI;
        const float* wc = W + ci * 81;
#pragma unroll
        for (int dt = 0; dt < 3; ++dt) {
            const int t_in = t0 + dt - 1;
            const int t_c = min(max(t_in, 0), TT - 1);
            const bool tv = (unsigned)t_in < TT;
#pragma unroll
            for (int dz = 0; dz < 3; ++dz) {
                const int z_in = z0 + dz - 1;
                const int z_c = min(max(z_in, 0), ZZ - 1);
                const bool tzvv = tv && ((unsigned)z_in < ZZ);
                const float* plane = xc + (size_t)t_c * SX_T + (size_t)z_c * SX_Z;
                const float* wb = wc + (dt * 3 + dz) * 9;
#pragma unroll
                for (int e = 0; e < 3; ++e) {
                    const int y_in = y + e - 1;
                    const int y_c = min(max(y_in, 0), YY - 1);
                    const bool v = tzvv && ((unsigned)y_in < YY);
                    float4 f = *(const float4*)(plane + y_c * XX + x0);
                    f.x = v ? f.x : 0.f; f.y = v ? f.y : 0.f;
                    f.z = v ? f.z : 0.f; f.w = v ? f.w : 0.f;
                    float hl = __shfl(f.w, (lane - 1) & 63, 64);
                    hl = (xg == 0) ? 0.f : hl;
                    float hr = __shfl(f.x, (lane + 1) & 63, 64);
                    hr = (xg == 15) ? 0.f : hr;
                    const float win[6] = {hl, f.x, f.y, f.z, f.w, hr};
#pragma unroll
                    for (int co = 0; co < COUT; ++co) {
                        const float* wp = wb + co * WCO + e * 3;
                        const float w0 = wp[0], w1 = wp[1], w2 = wp[2];
#pragma unroll
                        for (int xi = 0; xi < 4; ++xi) {
                            float a = acc[co][xi];
                            a = fmaf(win[xi], w0, a);
                            a = fmaf(win[xi + 1], w1, a);
                            a = fmaf(win[xi + 2], w2, a);
                            acc[co][xi] = a;
                        }
                    }
                }
            }
        }
    }
    const float b0 = b[0], b1 = b[1], b2 = b[2], b3 = b[3];
    float4 rr[COUT];
#pragma unroll
    for (int xi = 0; xi < 4; ++xi) {
        const float a0 = acc[0][xi] + b0, a1 = acc[1][xi] + b1;
        const float a2 = acc[2][xi] + b2, a3 = acc[3][xi] + b3;
        const float mm = fmaxf(fmaxf(a0, a1), fmaxf(a2, a3));
        const float e0 = __expf(a0 - mm), e1 = __expf(a1 - mm);
        const float e2 = __expf(a2 - mm), e3 = __expf(a3 - mm);
        const float inv = 1.f / (e0 + e1 + e2 + e3);
        ((float*)&rr[0])[xi] = e0 * inv; ((float*)&rr[1])[xi] = e1 * inv;
        ((float*)&rr[2])[xi] = e2 * inv; ((float*)&rr[3])[xi] = e3 * inv;
    }
    float* op = out + (size_t)t0 * SX_T + (size_t)z0 * SX_Z + (size_t)y * XX + x0;
#pragma unroll
    for (int co = 0; co < COUT; ++co)
        *(float4*)(op + (size_t)co * SX_CI) = rr[co];
}

extern "C" void kernel_launch(void* const* d_in, const int* in_sizes, int n_in,
                              void* d_out, int out_size, void* d_ws, size_t ws_size,
                              hipStream_t stream) {
    const float* x = (const float*)d_in[0];
    const float* W = (const float*)d_in[1];
    const float* b = (const float*)d_in[2];
    float* out = (float*)d_out;

    if (ws_size >= WS_NEED) {
        char* ws = (char*)d_ws;
        transpose_x<<<dim3(4, ZZ, TT), dim3(256), 0, stream>>>(x, ws);
        prep_B<<<dim3(5), dim3(256), 0, stream>>>(W, ws);
        conv_mfma<<<dim3(1280), dim3(64, 4), 0, stream>>>(ws, b, out);
    } else {
        conv4d_softmax_vec<<<dim3(4, ZZ, TT), dim3(64, 4), 0, stream>>>(x, W, b, out);
    }
}